// Round 16
// baseline (971.494 us; speedup 1.0000x reference)
//
#include <hip/hip_runtime.h>

// Bidirectional LSTM, B=64 S=256 I=H=512, f32 in/out.
// Persistent dataflow kernel: 256 WGs = 8 groups (2 dir x 4 batch-group) x 32 col-slices.
// Weights (fp16, MFMA-frag-packed) LDS-resident.
// Round 16 = round 11 (validated 763us) + ONE isolated delta: single-barrier distributed
// epilogue. Partial-sum LDS double-buffered by step parity (redb[2][..]); own-row partial
// kept in registers (12 LDS writes/thread, not 16); ONE __syncthreads per step.
// WAR-safe: read(t)@buf(t&1) precedes barrier(t+1); write(t+2)@same buf follows it.
// Sync protocol unchanged from r11: agent gate poll -> plain L2 pull (fast) -> tag verify;
// publish = plain store -> vmcnt(0) L2 ack -> agent counter bump. Slow path = r7 verbatim.

typedef float    f32x4 __attribute__((ext_vector_type(4)));
typedef _Float16 half8 __attribute__((ext_vector_type(8)));
typedef unsigned long long u64;

#define NB 64
#define NS 256
#define NI 512
#define NH 512

__device__ inline f32x4 zero4() { f32x4 v; v[0]=0.f; v[1]=0.f; v[2]=0.f; v[3]=0.f; return v; }

// ---------------- prep kernels ----------------

__global__ void conv_x(const float* __restrict__ x, _Float16* __restrict__ xb) {
    const int i = blockIdx.x * 256 + threadIdx.x;
    const float4 a = ((const float4*)x)[2*i];
    const float4 b = ((const float4*)x)[2*i+1];
    half8 o;
    o[0]=(_Float16)a.x; o[1]=(_Float16)a.y; o[2]=(_Float16)a.z; o[3]=(_Float16)a.w;
    o[4]=(_Float16)b.x; o[5]=(_Float16)b.y; o[6]=(_Float16)b.z; o[7]=(_Float16)b.w;
    ((half8*)xb)[i] = o;
}

// WP[d][s][p][kk][g][l][j] = W_{d,g}[p*512 + kk*32 + (l>>4)*8 + j][s*16 + (l&15)]
__global__ void pack_w(const float* __restrict__ Wi_f, const float* __restrict__ Wf_f,
                       const float* __restrict__ Wo_f, const float* __restrict__ Wc_f,
                       const float* __restrict__ Wi_b, const float* __restrict__ Wf_b,
                       const float* __restrict__ Wo_b, const float* __restrict__ Wc_b,
                       _Float16* __restrict__ WP) {
    const int idx = blockIdx.x * 256 + threadIdx.x;
    const int l  = idx & 63;
    const int g  = (idx >> 6) & 3;
    const int kk = (idx >> 8) & 15;
    const int p  = (idx >> 12) & 1;
    const int s  = (idx >> 13) & 31;
    const int d  = (idx >> 18) & 1;
    const float* W;
    if (d == 0) W = (g==0) ? Wi_f : (g==1) ? Wf_f : (g==2) ? Wo_f : Wc_f;
    else        W = (g==0) ? Wi_b : (g==1) ? Wf_b : (g==2) ? Wo_b : Wc_b;
    const int r0 = p*512 + kk*32 + (l >> 4)*8;
    const int c  = s*16 + (l & 15);
    half8 v;
    #pragma unroll
    for (int j = 0; j < 8; ++j) v[j] = (_Float16)W[(size_t)(r0 + j)*NH + c];
    *(half8*)(WP + (size_t)idx*8) = v;
}

__global__ void pack_bias(const float* __restrict__ bi_f, const float* __restrict__ bf_f,
                          const float* __restrict__ bo_f, const float* __restrict__ bc_f,
                          const float* __restrict__ bi_b, const float* __restrict__ bf_b,
                          const float* __restrict__ bo_b, const float* __restrict__ bc_b,
                          float* __restrict__ biasP) {
    const int i = blockIdx.x * 256 + threadIdx.x;
    const int c = i & 511, g = (i >> 9) & 3, d = (i >> 11) & 1;
    const float* b;
    if (d == 0) b = (g==0) ? bi_f : (g==1) ? bf_f : (g==2) ? bo_f : bc_f;
    else        b = (g==0) ? bi_b : (g==1) ? bf_b : (g==2) ? bo_b : bc_b;
    biasP[i] = b[c];
}

// ---------------- main persistent scan kernel ----------------
// grid 256 x 256. LDS: 128KiB packed weights + 24KiB double-buffered partials -> 1 WG/CU.
//
// hfrag layout (per group, per buf): [kk(16)][p(2)][lane64(64)][slot(4)] u32 tagged words.
//   word for h[row][c]: kk=c>>5, p=(c>>2)&1, lane64=((c>>3)&3)*16+row, slot=c&3.
// Consumer wave w, lane l, chunk c: two 16B-contiguous pulls per (kk,p), lane-stride 16B.

__global__ __launch_bounds__(256) void lstm_scan(
    const _Float16* __restrict__ xb,     // [64][256][512]
    const _Float16* __restrict__ WP,     // [2][32][2][16][4][64][8]
    const float*    __restrict__ biasP,  // [2][4][512]
    unsigned*       __restrict__ hfrag,  // [8 grp][2 buf][8192 u32]
    unsigned*       __restrict__ flags,  // [8][32] padded counters (8192 u32) + ctrl[24] after
    float*          __restrict__ out)    // [64][256][1024]
{
    __shared__ char  ldsw[131072];
    __shared__ float redb[2][4][4][3][64];  // [buf][wv][gate][rr(row!=wv)][lane]
    __shared__ unsigned mode_sh;

    const int wg  = blockIdx.x;
    const int g8  = wg & 7;           // group = (d,bg); wg&7 -> XCD (r4/r11-verified mapping)
    const int s   = wg >> 3;          // column slice (16 h-cols)
    const int d   = g8 >> 2;          // direction
    const int bg  = g8 & 3;           // batch group (16 rows)
    const int tid = threadIdx.x;
    const int w   = tid >> 6;         // wave 0..3 (K-split; owns rows r==w in epilogue)
    const int l   = tid & 63;

    unsigned* ctrl = flags + 8192;    // cnt[8], xmax[8], xmin[8]

    // ---- one-time XCD-homogeneity check for this group ----
    if (tid == 0) {
        unsigned xcc;
        asm volatile("s_getreg_b32 %0, hwreg(HW_REG_XCC_ID)" : "=s"(xcc));
        atomicMax(ctrl + 8 + g8, xcc);
        atomicMin(ctrl + 16 + g8, xcc);
        asm volatile("s_waitcnt vmcnt(0)" ::: "memory");   // max/min acked before arrival
        atomicAdd(ctrl + g8, 1u);
        int gu = 0; unsigned c;
        do {
            c = __hip_atomic_load(ctrl + g8, __ATOMIC_RELAXED, __HIP_MEMORY_SCOPE_AGENT);
        } while (c < 32u && ++gu < (1 << 22));
        const unsigned mx = __hip_atomic_load(ctrl + 8 + g8,  __ATOMIC_RELAXED, __HIP_MEMORY_SCOPE_AGENT);
        const unsigned mn = __hip_atomic_load(ctrl + 16 + g8, __ATOMIC_RELAXED, __HIP_MEMORY_SCOPE_AGENT);
        mode_sh = (gu < (1 << 22)) && (mn == mx);
    }

    // stage packed weight slice (128 KiB) into LDS
    {
        const uint4* src = (const uint4*)(WP + (size_t)(d*32 + s)*65536);
        uint4* dst = (uint4*)ldsw;
        #pragma unroll
        for (int i = 0; i < 32; ++i) dst[tid + i*256] = src[tid + i*256];
    }
    __syncthreads();
    const bool fast = (mode_sh != 0);    // wave-uniform

    // ---- per-thread epilogue ownership: (row_local, col_local) ----
    const int row_local = (l >> 4)*4 + w;     // 0..15
    const int col_local = l & 15;
    const int colg      = s*16 + col_local;   // h column 0..511
    const float bias0 = biasP[(d*4 + 0)*512 + colg];
    const float bias1 = biasP[(d*4 + 1)*512 + colg];
    const float bias2 = biasP[(d*4 + 2)*512 + colg];
    const float bias3 = biasP[(d*4 + 3)*512 + colg];
    float cstv = 0.f;                          // cell state (1 per thread)

    // publish offset for this thread's h word (within one buf, u32 units)
    const int myoff = (colg >> 5)*512 + ((colg >> 2) & 1)*256
                    + (((colg >> 3) & 3)*16 + row_local)*4 + (colg & 3);
    unsigned* grpfrag = hfrag + (size_t)g8 * 16384;   // 2 bufs x 8192
    unsigned* myflag  = flags + (size_t)(g8*32 + s) * 32;
    unsigned* pollp   = flags + (size_t)(g8*32 + w*8 + (l & 7)) * 32;

    f32x4 acc[4];
    #pragma unroll
    for (int g = 0; g < 4; ++g) acc[g] = zero4();

    bool dead = false;                    // sticky guard-trip (anti-hang)

    const int arow = bg*16 + (l & 15);    // x A-frag row = batch row
    const int kof  = (l >> 4) * 8;        // A/B frag k sub-offset
    const int kk0  = w * 4;               // this wave's first k-chunk

    for (int t = 0; t < NS; ++t) {
        const int u = d ? (NS - 1 - t) : t;   // time index in x/out

        // ---- (1) x A-frag loads + x-part MFMAs (independent of h) ----
        const _Float16* xp = xb + ((size_t)arow*NS + u)*NI + kof;
        half8 af[4];
        #pragma unroll
        for (int c = 0; c < 4; ++c) af[c] = *(const half8*)(xp + (kk0 + c)*32);
        #pragma unroll
        for (int c = 0; c < 4; ++c) {
            #pragma unroll
            for (int g = 0; g < 4; ++g) {
                const half8 b = *(const half8*)(ldsw + ((((kk0 + c)*4 + g) << 10) | (l << 4)));
                acc[g] = __builtin_amdgcn_mfma_f32_16x16x32_f16(af[c], b, acc[g], 0, 0, 0);
            }
        }

        // ---- (2) gate, (3) pull, (4) verify+retry, then h-MFMAs ----
        if (t > 0) {
            const unsigned tagv = (unsigned)t;
            const unsigned* gb = grpfrag + (size_t)(t & 1)*8192;
            u64 q[16];

            // gate: wave's lanes 0..7 hot-poll its 8 producer counters (agent/IF$)
            if (!dead) {
                const unsigned tgt4 = 4u * tagv;
                unsigned v = 0xFFFFFFFFu;
                int guard = 0;
                for (;;) {
                    if (l < 8) v = __hip_atomic_load(pollp, __ATOMIC_RELAXED,
                                                     __HIP_MEMORY_SCOPE_AGENT);
                    if (!__any(v < tgt4)) break;
                    if (++guard > (1 << 18)) { dead = true; break; }
                }
            }
            asm volatile("" ::: "memory");   // pin pulls after the gate

            // pull (single pass)
            if (fast) {
                #pragma unroll
                for (int c = 0; c < 4; ++c) {
                    const unsigned* blk = gb + (kk0 + c)*512;
                    const uint4 a  = *(const uint4*)(blk + l*4);
                    const uint4 b2 = *(const uint4*)(blk + 256 + l*4);
                    q[c*4+0] = ((u64)a.y  << 32) | a.x;
                    q[c*4+1] = ((u64)a.w  << 32) | a.z;
                    q[c*4+2] = ((u64)b2.y << 32) | b2.x;
                    q[c*4+3] = ((u64)b2.w << 32) | b2.z;
                }
            } else {
                #pragma unroll
                for (int c = 0; c < 4; ++c) {
                    const unsigned* blk = gb + (kk0 + c)*512;
                    const u64* p0 = (const u64*)(blk + l*4);
                    const u64* p1 = (const u64*)(blk + 256 + l*4);
                    q[c*4+0] = __hip_atomic_load(p0,     __ATOMIC_RELAXED, __HIP_MEMORY_SCOPE_AGENT);
                    q[c*4+1] = __hip_atomic_load(p0 + 1, __ATOMIC_RELAXED, __HIP_MEMORY_SCOPE_AGENT);
                    q[c*4+2] = __hip_atomic_load(p1,     __ATOMIC_RELAXED, __HIP_MEMORY_SCOPE_AGENT);
                    q[c*4+3] = __hip_atomic_load(p1 + 1, __ATOMIC_RELAXED, __HIP_MEMORY_SCOPE_AGENT);
                }
            }

            // verify; retry path differs per mode
            {
                int guard = 0;
                for (;;) {
                    unsigned bad = 0;
                    #pragma unroll
                    for (int j = 0; j < 16; ++j) {
                        const u64 v = q[j];
                        bad |= (((unsigned)(v >> 16) & 0xFFFFu) ^ tagv);
                        bad |= (((unsigned)(v >> 48))           ^ tagv);
                    }
                    if (!__any(bad != 0)) break;
                    if (dead || ++guard > (1 << 14)) { dead = true; break; }
                    if (fast) {
                        // deterministic L1 capacity eviction: 4 waves stream 64KiB of
                        // distinct lines, then plain re-pull (L2 is coherent in-XCD)
                        unsigned dum = 0;
                        const uint4* wp4 = (const uint4*)WP;
                        #pragma unroll
                        for (int i = 0; i < 16; ++i)
                            dum += wp4[(size_t)(w*1024 + i*64 + l)].x;
                        asm volatile("" :: "v"(dum));
                        asm volatile("" ::: "memory");
                        #pragma unroll
                        for (int c = 0; c < 4; ++c) {
                            const unsigned* blk = gb + (kk0 + c)*512;
                            const uint4 a  = *(const uint4*)(blk + l*4);
                            const uint4 b2 = *(const uint4*)(blk + 256 + l*4);
                            q[c*4+0] = ((u64)a.y  << 32) | a.x;
                            q[c*4+1] = ((u64)a.w  << 32) | a.z;
                            q[c*4+2] = ((u64)b2.y << 32) | b2.x;
                            q[c*4+3] = ((u64)b2.w << 32) | b2.z;
                        }
                    } else {
                        __builtin_amdgcn_s_sleep(1);
                        #pragma unroll
                        for (int c = 0; c < 4; ++c) {
                            const unsigned* blk = gb + (kk0 + c)*512;
                            const u64* p0 = (const u64*)(blk + l*4);
                            const u64* p1 = (const u64*)(blk + 256 + l*4);
                            q[c*4+0] = __hip_atomic_load(p0,     __ATOMIC_RELAXED, __HIP_MEMORY_SCOPE_AGENT);
                            q[c*4+1] = __hip_atomic_load(p0 + 1, __ATOMIC_RELAXED, __HIP_MEMORY_SCOPE_AGENT);
                            q[c*4+2] = __hip_atomic_load(p1,     __ATOMIC_RELAXED, __HIP_MEMORY_SCOPE_AGENT);
                            q[c*4+3] = __hip_atomic_load(p1 + 1, __ATOMIC_RELAXED, __HIP_MEMORY_SCOPE_AGENT);
                        }
                    }
                }
            }
            #pragma unroll
            for (int c = 0; c < 4; ++c) {
                union { unsigned uu[4]; half8 h; } hu;
                #pragma unroll
                for (int j = 0; j < 4; ++j) {
                    const u64 v = q[c*4 + j];
                    hu.uu[j] = ((unsigned)v & 0xFFFFu) | (((unsigned)(v >> 32)) << 16);
                }
                const half8 ah = hu.h;
                #pragma unroll
                for (int g = 0; g < 4; ++g) {
                    const half8 b = *(const half8*)(ldsw + ((((16 + kk0 + c)*4 + g) << 10) | (l << 4)));
                    acc[g] = __builtin_amdgcn_mfma_f32_16x16x32_f16(ah, b, acc[g], 0, 0, 0);
                }
            }
        }

        // ---- (5) single-barrier distributed epilogue (double-buffered partials) ----
        const int bsel = t & 1;
        #pragma unroll
        for (int g = 0; g < 4; ++g) {
            #pragma unroll
            for (int r = 0; r < 4; ++r) {
                if (r != w) redb[bsel][w][g][r - (r > w)][l] = acc[g][r];
            }
        }
        __syncthreads();   // ONE barrier: partials(t) visible; WAR vs step t+2 separated
                           // by barrier(t+1) (see header proof)
        {
            float sg[4];
            #pragma unroll
            for (int g = 0; g < 4; ++g) {
                float sv = acc[g][w];   // own-row partial kept in registers
                #pragma unroll
                for (int wv = 0; wv < 4; ++wv) {
                    if (wv != w) sv += redb[bsel][wv][g][w - (w > wv)][l];
                }
                sg[g] = sv;
            }
            const float ig = 1.f / (1.f + __expf(-(sg[0] + bias0)));
            const float fg = 1.f / (1.f + __expf(-(sg[1] + bias1)));
            const float og = 1.f / (1.f + __expf(-(sg[2] + bias2)));
            const float gv = sg[3] + bias3;
            const float gg = 1.f - 2.f / (__expf(2.f*gv) + 1.f);        // tanh
            cstv = fg*cstv + ig*gg;
            const float hvv = og * (1.f - 2.f / (__expf(2.f*cstv) + 1.f));

            if (t + 1 < NS) {
                const unsigned short hb = __builtin_bit_cast(unsigned short, (_Float16)hvv);
                const unsigned word = ((unsigned)(t + 1) << 16) | (unsigned)hb;
                unsigned* dst = grpfrag + (size_t)((t + 1) & 1)*8192 + myoff;
                if (fast) {
                    *dst = word;                                     // plain -> shared L2
                    asm volatile("s_waitcnt vmcnt(0)" ::: "memory"); // L2 ack before bump
                    if (l == 0)
                        (void)__hip_atomic_fetch_add(myflag, 1u, __ATOMIC_RELAXED,
                                                     __HIP_MEMORY_SCOPE_AGENT);
                } else {
                    __hip_atomic_store(dst, word, __ATOMIC_RELAXED, __HIP_MEMORY_SCOPE_AGENT);
                    if (l == 0)
                        (void)__hip_atomic_fetch_add(myflag, 1u, __ATOMIC_RELAXED,
                                                     __HIP_MEMORY_SCOPE_AGENT);
                }
            }
            // out store after the bump (off the sync path)
            out[((size_t)(bg*16 + row_local)*NS + u)*1024 + (d << 9) + colg] = hvv;
        }
        #pragma unroll
        for (int g = 0; g < 4; ++g) acc[g] = zero4();
    }
}

// ---------------- launch ----------------

extern "C" void kernel_launch(void* const* d_in, const int* in_sizes, int n_in,
                              void* d_out, int out_size, void* d_ws, size_t ws_size,
                              hipStream_t stream) {
    const float* x = (const float*)d_in[0];
    char* ws = (char*)d_ws;
    _Float16* xb    = (_Float16*)ws;                                   // 16 MiB
    _Float16* WP    = (_Float16*)(ws + (16u << 20));                   // 8 MiB
    float*    biasP = (float*)(ws + (24u << 20));                      // 16 KiB
    unsigned* hfrag = (unsigned*)(ws + (24u << 20) + (64u << 10));     // 512 KiB frag-order h
    unsigned* flags = (unsigned*)(ws + (24u << 20) + (64u << 10) + (512u << 10)); // counters+ctrl

    // zero tags + counters + ctrl{cnt,xmax}; xmin = 0xFFFFFFFF  (graph-replay deterministic)
    hipMemsetAsync(hfrag, 0, (512u << 10) + (32u << 10) + 64u, stream);
    hipMemsetAsync((char*)flags + (32u << 10) + 64u, 0xFF, 32u, stream);
    conv_x<<<4096, 256, 0, stream>>>(x, xb);
    // gate order g: 0=i(Wi) 1=f(Wf) 2=o(Wo) 3=g(Wc)
    pack_w<<<2048, 256, 0, stream>>>(
        (const float*)d_in[1],  (const float*)d_in[3],  (const float*)d_in[7],  (const float*)d_in[5],
        (const float*)d_in[9],  (const float*)d_in[11], (const float*)d_in[15], (const float*)d_in[13], WP);
    pack_bias<<<16, 256, 0, stream>>>(
        (const float*)d_in[2],  (const float*)d_in[4],  (const float*)d_in[8],  (const float*)d_in[6],
        (const float*)d_in[10], (const float*)d_in[12], (const float*)d_in[16], (const float*)d_in[14], biasP);
    lstm_scan<<<256, 256, 0, stream>>>(xb, WP, biasP, hfrag, flags, (float*)d_out);
}

// Round 17
// 762.416 us; speedup vs baseline: 1.2742x; 1.2742x over previous
//
#include <hip/hip_runtime.h>

// Bidirectional LSTM, B=64 S=256 I=H=512, f32 in/out.
// Persistent dataflow kernel: 256 WGs = 8 groups (2 dir x 4 batch-group) x 32 col-slices.
// Weights (fp16, MFMA-frag-packed) LDS-resident.
// FINAL = round-11 kernel verbatim (best validated: 763us, replay-stable; reproduced r15).
//   fast (XCD-homogeneous group, runtime XCC_ID-checked): plain write-through h stores ->
//   s_waitcnt vmcnt(0) (L2 ack) -> agent counter bump; agent-scope gate poll; plain uint4
//   pulls from the shared XCD L2 (2-step reuse distance -> natural L1 turnover); per-word
//   step tags verified (authoritative; tag match proves step-exact data).
//   slow (fallback): round-7 agent-scope (IF$) protocol verbatim.
// Converged: isolated tests of every structural alternative regressed (r8 gate-free +71%,
// r9 gate-first +61%, r10 poll-pipeline +4%, r12/r13 L2-RMW gate corrupt/+7%, r14
// speculative skip incorrect, r16 single-barrier +27%). Residual ~3us/step = IF$ counter
// visibility+detect + L2 pull + h-MFMA + 2 barriers (wave phase-lock) + max-of-8 producer
// jitter, x256 inherently serial steps — a latency floor, not a BW/compute roofline.

typedef float    f32x4 __attribute__((ext_vector_type(4)));
typedef _Float16 half8 __attribute__((ext_vector_type(8)));
typedef unsigned long long u64;

#define NB 64
#define NS 256
#define NI 512
#define NH 512

__device__ inline f32x4 zero4() { f32x4 v; v[0]=0.f; v[1]=0.f; v[2]=0.f; v[3]=0.f; return v; }

// ---------------- prep kernels ----------------

__global__ void conv_x(const float* __restrict__ x, _Float16* __restrict__ xb) {
    const int i = blockIdx.x * 256 + threadIdx.x;
    const float4 a = ((const float4*)x)[2*i];
    const float4 b = ((const float4*)x)[2*i+1];
    half8 o;
    o[0]=(_Float16)a.x; o[1]=(_Float16)a.y; o[2]=(_Float16)a.z; o[3]=(_Float16)a.w;
    o[4]=(_Float16)b.x; o[5]=(_Float16)b.y; o[6]=(_Float16)b.z; o[7]=(_Float16)b.w;
    ((half8*)xb)[i] = o;
}

// WP[d][s][p][kk][g][l][j] = W_{d,g}[p*512 + kk*32 + (l>>4)*8 + j][s*16 + (l&15)]
__global__ void pack_w(const float* __restrict__ Wi_f, const float* __restrict__ Wf_f,
                       const float* __restrict__ Wo_f, const float* __restrict__ Wc_f,
                       const float* __restrict__ Wi_b, const float* __restrict__ Wf_b,
                       const float* __restrict__ Wo_b, const float* __restrict__ Wc_b,
                       _Float16* __restrict__ WP) {
    const int idx = blockIdx.x * 256 + threadIdx.x;
    const int l  = idx & 63;
    const int g  = (idx >> 6) & 3;
    const int kk = (idx >> 8) & 15;
    const int p  = (idx >> 12) & 1;
    const int s  = (idx >> 13) & 31;
    const int d  = (idx >> 18) & 1;
    const float* W;
    if (d == 0) W = (g==0) ? Wi_f : (g==1) ? Wf_f : (g==2) ? Wo_f : Wc_f;
    else        W = (g==0) ? Wi_b : (g==1) ? Wf_b : (g==2) ? Wo_b : Wc_b;
    const int r0 = p*512 + kk*32 + (l >> 4)*8;
    const int c  = s*16 + (l & 15);
    half8 v;
    #pragma unroll
    for (int j = 0; j < 8; ++j) v[j] = (_Float16)W[(size_t)(r0 + j)*NH + c];
    *(half8*)(WP + (size_t)idx*8) = v;
}

__global__ void pack_bias(const float* __restrict__ bi_f, const float* __restrict__ bf_f,
                          const float* __restrict__ bo_f, const float* __restrict__ bc_f,
                          const float* __restrict__ bi_b, const float* __restrict__ bf_b,
                          const float* __restrict__ bo_b, const float* __restrict__ bc_b,
                          float* __restrict__ biasP) {
    const int i = blockIdx.x * 256 + threadIdx.x;
    const int c = i & 511, g = (i >> 9) & 3, d = (i >> 11) & 1;
    const float* b;
    if (d == 0) b = (g==0) ? bi_f : (g==1) ? bf_f : (g==2) ? bo_f : bc_f;
    else        b = (g==0) ? bi_b : (g==1) ? bf_b : (g==2) ? bo_b : bc_b;
    biasP[i] = b[c];
}

// ---------------- main persistent scan kernel ----------------
// grid 256 x 256. LDS: 128KiB packed weights + 16KiB partial-sum buffer -> 1 WG/CU.
//
// hfrag layout (per group, per buf): [kk(16)][p(2)][lane64(64)][slot(4)] u32 tagged words.
//   word for h[row][c]: kk=c>>5, p=(c>>2)&1, lane64=((c>>3)&3)*16+row, slot=c&3.
// Consumer wave w, lane l, chunk c: two 16B-contiguous pulls per (kk,p), lane-stride 16B.

__global__ __launch_bounds__(256) void lstm_scan(
    const _Float16* __restrict__ xb,     // [64][256][512]
    const _Float16* __restrict__ WP,     // [2][32][2][16][4][64][8]
    const float*    __restrict__ biasP,  // [2][4][512]
    unsigned*       __restrict__ hfrag,  // [8 grp][2 buf][8192 u32]
    unsigned*       __restrict__ flags,  // [8][32] padded counters (8192 u32) + ctrl[24] after
    float*          __restrict__ out)    // [64][256][1024]
{
    __shared__ char  ldsw[131072];
    __shared__ float redb[4][4][4][64];  // [wv][gate][r][lane]
    __shared__ unsigned mode_sh;

    const int wg  = blockIdx.x;
    const int g8  = wg & 7;           // group = (d,bg); wg&7 -> XCD (r4/r11-verified mapping)
    const int s   = wg >> 3;          // column slice (16 h-cols)
    const int d   = g8 >> 2;          // direction
    const int bg  = g8 & 3;           // batch group (16 rows)
    const int tid = threadIdx.x;
    const int w   = tid >> 6;         // wave 0..3 (K-split; owns rows r==w in epilogue)
    const int l   = tid & 63;

    unsigned* ctrl = flags + 8192;    // cnt[8], xmax[8], xmin[8]

    // ---- one-time XCD-homogeneity check for this group ----
    if (tid == 0) {
        unsigned xcc;
        asm volatile("s_getreg_b32 %0, hwreg(HW_REG_XCC_ID)" : "=s"(xcc));
        atomicMax(ctrl + 8 + g8, xcc);
        atomicMin(ctrl + 16 + g8, xcc);
        asm volatile("s_waitcnt vmcnt(0)" ::: "memory");   // max/min acked before arrival
        atomicAdd(ctrl + g8, 1u);
        int gu = 0; unsigned c;
        do {
            c = __hip_atomic_load(ctrl + g8, __ATOMIC_RELAXED, __HIP_MEMORY_SCOPE_AGENT);
        } while (c < 32u && ++gu < (1 << 22));
        const unsigned mx = __hip_atomic_load(ctrl + 8 + g8,  __ATOMIC_RELAXED, __HIP_MEMORY_SCOPE_AGENT);
        const unsigned mn = __hip_atomic_load(ctrl + 16 + g8, __ATOMIC_RELAXED, __HIP_MEMORY_SCOPE_AGENT);
        mode_sh = (gu < (1 << 22)) && (mn == mx);
    }

    // stage packed weight slice (128 KiB) into LDS
    {
        const uint4* src = (const uint4*)(WP + (size_t)(d*32 + s)*65536);
        uint4* dst = (uint4*)ldsw;
        #pragma unroll
        for (int i = 0; i < 32; ++i) dst[tid + i*256] = src[tid + i*256];
    }
    __syncthreads();
    const bool fast = (mode_sh != 0);    // wave-uniform

    // ---- per-thread epilogue ownership: (row_local, col_local) ----
    const int row_local = (l >> 4)*4 + w;     // 0..15
    const int col_local = l & 15;
    const int colg      = s*16 + col_local;   // h column 0..511
    const float bias0 = biasP[(d*4 + 0)*512 + colg];
    const float bias1 = biasP[(d*4 + 1)*512 + colg];
    const float bias2 = biasP[(d*4 + 2)*512 + colg];
    const float bias3 = biasP[(d*4 + 3)*512 + colg];
    float cstv = 0.f;                          // cell state (1 per thread)

    // publish offset for this thread's h word (within one buf, u32 units)
    const int myoff = (colg >> 5)*512 + ((colg >> 2) & 1)*256
                    + (((colg >> 3) & 3)*16 + row_local)*4 + (colg & 3);
    unsigned* grpfrag = hfrag + (size_t)g8 * 16384;   // 2 bufs x 8192
    unsigned* myflag  = flags + (size_t)(g8*32 + s) * 32;
    unsigned* pollp   = flags + (size_t)(g8*32 + w*8 + (l & 7)) * 32;

    f32x4 acc[4];
    #pragma unroll
    for (int g = 0; g < 4; ++g) acc[g] = zero4();

    bool dead = false;                    // sticky guard-trip (anti-hang)

    const int arow = bg*16 + (l & 15);    // x A-frag row = batch row
    const int kof  = (l >> 4) * 8;        // A/B frag k sub-offset
    const int kk0  = w * 4;               // this wave's first k-chunk

    for (int t = 0; t < NS; ++t) {
        const int u = d ? (NS - 1 - t) : t;   // time index in x/out

        // ---- (1) x A-frag loads + x-part MFMAs (independent of h) ----
        const _Float16* xp = xb + ((size_t)arow*NS + u)*NI + kof;
        half8 af[4];
        #pragma unroll
        for (int c = 0; c < 4; ++c) af[c] = *(const half8*)(xp + (kk0 + c)*32);
        #pragma unroll
        for (int c = 0; c < 4; ++c) {
            #pragma unroll
            for (int g = 0; g < 4; ++g) {
                const half8 b = *(const half8*)(ldsw + ((((kk0 + c)*4 + g) << 10) | (l << 4)));
                acc[g] = __builtin_amdgcn_mfma_f32_16x16x32_f16(af[c], b, acc[g], 0, 0, 0);
            }
        }

        // ---- (2) gate, (3) pull, (4) verify+retry, then h-MFMAs ----
        if (t > 0) {
            const unsigned tagv = (unsigned)t;
            const unsigned* gb = grpfrag + (size_t)(t & 1)*8192;
            u64 q[16];

            // gate: wave's lanes 0..7 hot-poll its 8 producer counters (agent/IF$)
            if (!dead) {
                const unsigned tgt4 = 4u * tagv;
                unsigned v = 0xFFFFFFFFu;
                int guard = 0;
                for (;;) {
                    if (l < 8) v = __hip_atomic_load(pollp, __ATOMIC_RELAXED,
                                                     __HIP_MEMORY_SCOPE_AGENT);
                    if (!__any(v < tgt4)) break;
                    if (++guard > (1 << 18)) { dead = true; break; }
                }
            }
            asm volatile("" ::: "memory");   // pin pulls after the gate

            // pull (single pass)
            if (fast) {
                #pragma unroll
                for (int c = 0; c < 4; ++c) {
                    const unsigned* blk = gb + (kk0 + c)*512;
                    const uint4 a  = *(const uint4*)(blk + l*4);
                    const uint4 b2 = *(const uint4*)(blk + 256 + l*4);
                    q[c*4+0] = ((u64)a.y  << 32) | a.x;
                    q[c*4+1] = ((u64)a.w  << 32) | a.z;
                    q[c*4+2] = ((u64)b2.y << 32) | b2.x;
                    q[c*4+3] = ((u64)b2.w << 32) | b2.z;
                }
            } else {
                #pragma unroll
                for (int c = 0; c < 4; ++c) {
                    const unsigned* blk = gb + (kk0 + c)*512;
                    const u64* p0 = (const u64*)(blk + l*4);
                    const u64* p1 = (const u64*)(blk + 256 + l*4);
                    q[c*4+0] = __hip_atomic_load(p0,     __ATOMIC_RELAXED, __HIP_MEMORY_SCOPE_AGENT);
                    q[c*4+1] = __hip_atomic_load(p0 + 1, __ATOMIC_RELAXED, __HIP_MEMORY_SCOPE_AGENT);
                    q[c*4+2] = __hip_atomic_load(p1,     __ATOMIC_RELAXED, __HIP_MEMORY_SCOPE_AGENT);
                    q[c*4+3] = __hip_atomic_load(p1 + 1, __ATOMIC_RELAXED, __HIP_MEMORY_SCOPE_AGENT);
                }
            }

            // verify; retry path differs per mode
            {
                int guard = 0;
                for (;;) {
                    unsigned bad = 0;
                    #pragma unroll
                    for (int j = 0; j < 16; ++j) {
                        const u64 v = q[j];
                        bad |= (((unsigned)(v >> 16) & 0xFFFFu) ^ tagv);
                        bad |= (((unsigned)(v >> 48))           ^ tagv);
                    }
                    if (!__any(bad != 0)) break;
                    if (dead || ++guard > (1 << 14)) { dead = true; break; }
                    if (fast) {
                        // deterministic L1 capacity eviction: 4 waves stream 64KiB of
                        // distinct lines, then plain re-pull (L2 is coherent in-XCD)
                        unsigned dum = 0;
                        const uint4* wp4 = (const uint4*)WP;
                        #pragma unroll
                        for (int i = 0; i < 16; ++i)
                            dum += wp4[(size_t)(w*1024 + i*64 + l)].x;
                        asm volatile("" :: "v"(dum));
                        asm volatile("" ::: "memory");
                        #pragma unroll
                        for (int c = 0; c < 4; ++c) {
                            const unsigned* blk = gb + (kk0 + c)*512;
                            const uint4 a  = *(const uint4*)(blk + l*4);
                            const uint4 b2 = *(const uint4*)(blk + 256 + l*4);
                            q[c*4+0] = ((u64)a.y  << 32) | a.x;
                            q[c*4+1] = ((u64)a.w  << 32) | a.z;
                            q[c*4+2] = ((u64)b2.y << 32) | b2.x;
                            q[c*4+3] = ((u64)b2.w << 32) | b2.z;
                        }
                    } else {
                        __builtin_amdgcn_s_sleep(1);
                        #pragma unroll
                        for (int c = 0; c < 4; ++c) {
                            const unsigned* blk = gb + (kk0 + c)*512;
                            const u64* p0 = (const u64*)(blk + l*4);
                            const u64* p1 = (const u64*)(blk + 256 + l*4);
                            q[c*4+0] = __hip_atomic_load(p0,     __ATOMIC_RELAXED, __HIP_MEMORY_SCOPE_AGENT);
                            q[c*4+1] = __hip_atomic_load(p0 + 1, __ATOMIC_RELAXED, __HIP_MEMORY_SCOPE_AGENT);
                            q[c*4+2] = __hip_atomic_load(p1,     __ATOMIC_RELAXED, __HIP_MEMORY_SCOPE_AGENT);
                            q[c*4+3] = __hip_atomic_load(p1 + 1, __ATOMIC_RELAXED, __HIP_MEMORY_SCOPE_AGENT);
                        }
                    }
                }
            }
            #pragma unroll
            for (int c = 0; c < 4; ++c) {
                union { unsigned uu[4]; half8 h; } hu;
                #pragma unroll
                for (int j = 0; j < 4; ++j) {
                    const u64 v = q[c*4 + j];
                    hu.uu[j] = ((unsigned)v & 0xFFFFu) | (((unsigned)(v >> 32)) << 16);
                }
                const half8 ah = hu.h;
                #pragma unroll
                for (int g = 0; g < 4; ++g) {
                    const half8 b = *(const half8*)(ldsw + ((((16 + kk0 + c)*4 + g) << 10) | (l << 4)));
                    acc[g] = __builtin_amdgcn_mfma_f32_16x16x32_f16(ah, b, acc[g], 0, 0, 0);
                }
            }
        }

        // ---- (5) cross-wave partial exchange + distributed epilogue ----
        __syncthreads();   // BARRIER1: prev-step epilogue reads of redb are done
        #pragma unroll
        for (int g = 0; g < 4; ++g) {
            #pragma unroll
            for (int r = 0; r < 4; ++r) redb[w][g][r][l] = acc[g][r];
        }
        __syncthreads();   // BARRIER2: all partials visible (also phase-locks waves)
        {
            float s0 = 0.f, s1 = 0.f, s2 = 0.f, s3 = 0.f;
            #pragma unroll
            for (int wv = 0; wv < 4; ++wv) {
                s0 += redb[wv][0][w][l];
                s1 += redb[wv][1][w][l];
                s2 += redb[wv][2][w][l];
                s3 += redb[wv][3][w][l];
            }
            const float ig = 1.f / (1.f + __expf(-(s0 + bias0)));
            const float fg = 1.f / (1.f + __expf(-(s1 + bias1)));
            const float og = 1.f / (1.f + __expf(-(s2 + bias2)));
            const float gv = s3 + bias3;
            const float gg = 1.f - 2.f / (__expf(2.f*gv) + 1.f);        // tanh
            cstv = fg*cstv + ig*gg;
            const float hvv = og * (1.f - 2.f / (__expf(2.f*cstv) + 1.f));

            if (t + 1 < NS) {
                const unsigned short hb = __builtin_bit_cast(unsigned short, (_Float16)hvv);
                const unsigned word = ((unsigned)(t + 1) << 16) | (unsigned)hb;
                unsigned* dst = grpfrag + (size_t)((t + 1) & 1)*8192 + myoff;
                if (fast) {
                    *dst = word;                                     // plain -> shared L2
                    asm volatile("s_waitcnt vmcnt(0)" ::: "memory"); // L2 ack before bump
                    if (l == 0)
                        (void)__hip_atomic_fetch_add(myflag, 1u, __ATOMIC_RELAXED,
                                                     __HIP_MEMORY_SCOPE_AGENT);
                } else {
                    __hip_atomic_store(dst, word, __ATOMIC_RELAXED, __HIP_MEMORY_SCOPE_AGENT);
                    if (l == 0)
                        (void)__hip_atomic_fetch_add(myflag, 1u, __ATOMIC_RELAXED,
                                                     __HIP_MEMORY_SCOPE_AGENT);
                }
            }
            // out store after the bump (off the sync path)
            out[((size_t)(bg*16 + row_local)*NS + u)*1024 + (d << 9) + colg] = hvv;
        }
        #pragma unroll
        for (int g = 0; g < 4; ++g) acc[g] = zero4();
    }
}

// ---------------- launch ----------------

extern "C" void kernel_launch(void* const* d_in, const int* in_sizes, int n_in,
                              void* d_out, int out_size, void* d_ws, size_t ws_size,
                              hipStream_t stream) {
    const float* x = (const float*)d_in[0];
    char* ws = (char*)d_ws;
    _Float16* xb    = (_Float16*)ws;                                   // 16 MiB
    _Float16* WP    = (_Float16*)(ws + (16u << 20));                   // 8 MiB
    float*    biasP = (float*)(ws + (24u << 20));                      // 16 KiB
    unsigned* hfrag = (unsigned*)(ws + (24u << 20) + (64u << 10));     // 512 KiB frag-order h
    unsigned* flags = (unsigned*)(ws + (24u << 20) + (64u << 10) + (512u << 10)); // counters+ctrl

    // zero tags + counters + ctrl{cnt,xmax}; xmin = 0xFFFFFFFF  (graph-replay deterministic)
    hipMemsetAsync(hfrag, 0, (512u << 10) + (32u << 10) + 64u, stream);
    hipMemsetAsync((char*)flags + (32u << 10) + 64u, 0xFF, 32u, stream);
    conv_x<<<4096, 256, 0, stream>>>(x, xb);
    // gate order g: 0=i(Wi) 1=f(Wf) 2=o(Wo) 3=g(Wc)
    pack_w<<<2048, 256, 0, stream>>>(
        (const float*)d_in[1],  (const float*)d_in[3],  (const float*)d_in[7],  (const float*)d_in[5],
        (const float*)d_in[9],  (const float*)d_in[11], (const float*)d_in[15], (const float*)d_in[13], WP);
    pack_bias<<<16, 256, 0, stream>>>(
        (const float*)d_in[2],  (const float*)d_in[4],  (const float*)d_in[8],  (const float*)d_in[6],
        (const float*)d_in[10], (const float*)d_in[12], (const float*)d_in[16], (const float*)d_in[14], biasP);
    lstm_scan<<<256, 256, 0, stream>>>(xb, WP, biasP, hfrag, flags, (float*)d_out);
}